// Round 5
// baseline (217.504 us; speedup 1.0000x reference)
//
#include <hip/hip_runtime.h>
#include <hip/hip_bf16.h>
#include <stdint.h>

#define NN 10000
#define NE 320000
#define NH 4

typedef __attribute__((ext_vector_type(8))) short s16x8;
typedef __attribute__((ext_vector_type(4))) float f32x4;
typedef __attribute__((ext_vector_type(8))) unsigned short u16x8;

static __device__ __forceinline__ float b2f(unsigned short u) {
    union { unsigned int i; float f; } x; x.i = ((unsigned int)u) << 16; return x.f;
}
static __device__ __forceinline__ unsigned short f2b(float f) {
    unsigned int u = __float_as_uint(f);
    unsigned int r = (u + 0x7fffu + ((u >> 16) & 1u)) >> 16;
    return (unsigned short)r;
}

// ---------------- fused prep: dtype flag + canon small tensors + W transposes + deg zero ----
// Each block recomputes the bf16-vs-fp32 flag locally from h[0:8192] (L2-resident) so no
// cross-kernel flag dependency exists inside this kernel.
__global__ __launch_bounds__(256) void k_prep(const unsigned short* __restrict__ hraw,
                        const void* __restrict__ W1, const void* __restrict__ W2,
                        const void* al1, const void* ar1, const void* b1,
                        const void* al2, const void* ar2, const void* b2,
                        unsigned short* __restrict__ W1T, unsigned short* __restrict__ W2T,
                        unsigned short* __restrict__ canon, int* __restrict__ deg,
                        int* __restrict__ flag) {
    __shared__ int sb[256];
    int t = threadIdx.x;
    int cnt = 0;
    for (int i = t; i < 8192; i += 256) {
        unsigned short u = hraw[i];
        int e = (u >> 7) & 0xFF;
        cnt += (e >= 97 && e <= 157) ? 1 : 0;   // |x| in [2^-30, 2^30]
    }
    sb[t] = cnt;
    __syncthreads();
    for (int o = 128; o > 0; o >>= 1) {
        if (t < o) sb[t] += sb[t + o];
        __syncthreads();
    }
    int isbf = (sb[0] >= 6963) ? 1 : 0;         // 85% of 8192

    int idx = blockIdx.x * 256 + t;
    if (idx < 65536) {                           // W1T[n*256+k] = W1[k*256+n]
        int n = idx >> 8, k = idx & 255;
        W1T[idx] = isbf ? ((const unsigned short*)W1)[k * 256 + n]
                        : f2b(((const float*)W1)[k * 256 + n]);
    } else if (idx < 81920) {                    // W2T[n*256+k] = W2[k*64+n]
        int j = idx - 65536;
        int n = j >> 8, k = j & 255;
        W2T[j] = isbf ? ((const unsigned short*)W2)[k * 64 + n]
                      : f2b(((const float*)W2)[k * 64 + n]);
    } else if (idx < 82880) {                    // small tensors -> canon
        int j = idx - 81920;
        const void* srcp; int q;
        if      (j < 256) { srcp = al1; q = j; }
        else if (j < 512) { srcp = ar1; q = j - 256; }
        else if (j < 768) { srcp = b1;  q = j - 512; }
        else if (j < 832) { srcp = al2; q = j - 768; }
        else if (j < 896) { srcp = ar2; q = j - 832; }
        else              { srcp = b2;  q = j - 896; }
        canon[j] = isbf ? ((const unsigned short*)srcp)[q] : f2b(((const float*)srcp)[q]);
    } else if (idx < 92880) {                    // zero deg[10000]
        deg[idx - 82880] = 0;
    } else if (idx == 92880) {
        flag[0] = isbf;
    }
}

// ---------------- CSR build ----------------
__global__ void k_deg(const int* __restrict__ dst, int* __restrict__ deg, int e) {
    int i = blockIdx.x * 256 + threadIdx.x;
    if (i < e) atomicAdd(&deg[dst[i]], 1);
}

// single block, 256 threads, 40 contiguous elements per thread (256*40 >= NN)
__global__ void k_scan(const int* __restrict__ deg, int* __restrict__ offs,
                       int* __restrict__ cursor, int n) {
    __shared__ int wtot[4];
    int t = threadIdx.x;
    int lane = t & 63, wv = t >> 6;
    int base = t * 40;
    int sum = 0;
#pragma unroll
    for (int j = 0; j < 40; ++j) {
        int i = base + j;
        sum += (i < n) ? deg[i] : 0;
    }
    int x = sum;
    for (int o = 1; o < 64; o <<= 1) {
        int y = __shfl_up(x, o, 64);
        if (lane >= o) x += y;
    }
    if (lane == 63) wtot[wv] = x;
    __syncthreads();
    int wbase = 0;
    for (int k = 0; k < wv; ++k) wbase += wtot[k];
    int run = wbase + x - sum;
    for (int j = 0; j < 40; ++j) {
        int i = base + j;
        if (i < n) {
            offs[i] = run;
            cursor[i] = run;
            run += deg[i];
        }
    }
    if (t == 255) offs[n] = run;
}

__global__ void k_scatter(const int* __restrict__ src, const int* __restrict__ dst,
                          int* __restrict__ cursor, int* __restrict__ csr_src, int e) {
    int i = blockIdx.x * 256 + threadIdx.x;
    if (i < e) {
        int slot = atomicAdd(&cursor[dst[i]], 1);
        csr_src[slot] = src[i];
    }
}

// ---------------- bf16 MFMA GEMM, no LDS: direct 16B fragment loads ----------------
// C[M, H*64] = A[M,256] @ B; BT is [H*64, 256] bf16. Grid (ceil(M/64), H), 4 waves/block;
// wave w -> rows m0+w*16..+15, cols = head's 64. Fused el/er epilogue.
__global__ __launch_bounds__(256) void k_gemm(const void* __restrict__ A,
                                              const unsigned short* __restrict__ BT,
                                              unsigned short* __restrict__ C,
                                              float* __restrict__ el, float* __restrict__ er,
                                              const unsigned short* __restrict__ al,
                                              const unsigned short* __restrict__ ar,
                                              int M, int N, int H,
                                              const int* __restrict__ flagp) {
    int t = threadIdx.x;
    int wave = t >> 6, lane = t & 63;
    int head = blockIdx.y;
    int m0 = blockIdx.x * 64;
    int aRow = m0 + wave * 16 + (lane & 15);
    int aR = (aRow < M) ? aRow : M - 1;          // clamp loads; stores guarded
    int kq = (lane >> 4) * 8;                    // k sub-offset within 32-slab
    int a_isbf = flagp ? flagp[0] : 1;
    const unsigned short* Ab = (const unsigned short*)A;
    const float*          Af = (const float*)A;
    const unsigned short* Bh = BT + (size_t)head * 64 * 256;
    f32x4 acc[4] = {};

#pragma unroll
    for (int k0 = 0; k0 < 256; k0 += 32) {
        s16x8 afr;
        if (a_isbf) {
            afr = *(const s16x8*)&Ab[(size_t)aR * 256 + k0 + kq];
        } else {
            const float* pf = &Af[(size_t)aR * 256 + k0 + kq];
            float4 x0 = *(const float4*)pf;
            float4 x1 = *(const float4*)(pf + 4);
            afr[0] = (short)f2b(x0.x); afr[1] = (short)f2b(x0.y);
            afr[2] = (short)f2b(x0.z); afr[3] = (short)f2b(x0.w);
            afr[4] = (short)f2b(x1.x); afr[5] = (short)f2b(x1.y);
            afr[6] = (short)f2b(x1.z); afr[7] = (short)f2b(x1.w);
        }
#pragma unroll
        for (int nt = 0; nt < 4; ++nt) {
            s16x8 bfr = *(const s16x8*)&Bh[(size_t)(nt * 16 + (lane & 15)) * 256 + k0 + kq];
            acc[nt] = __builtin_amdgcn_mfma_f32_16x16x32_bf16(afr, bfr, acc[nt], 0, 0, 0);
        }
    }

    // C store (bf16), keeping rounded values for the el/er dot so edge kernels re-read match
    int col0 = head * 64 + (lane & 15);
    int r0 = m0 + wave * 16 + (lane >> 4) * 4;
    float cr[4][4];
#pragma unroll
    for (int nt = 0; nt < 4; ++nt) {
        int col = col0 + nt * 16;
#pragma unroll
        for (int i = 0; i < 4; ++i) {
            unsigned short cb = f2b(acc[nt][i]);
            cr[nt][i] = b2f(cb);
            int r = r0 + i;
            if (r < M) C[(size_t)r * N + col] = cb;
        }
    }

    float alv[4], arv[4];
#pragma unroll
    for (int nt = 0; nt < 4; ++nt) {
        int c = (lane & 15) + nt * 16;
        alv[nt] = b2f(al[head * 64 + c]);
        arv[nt] = b2f(ar[head * 64 + c]);
    }
#pragma unroll
    for (int i = 0; i < 4; ++i) {
        float pl = 0.f, pr = 0.f;
#pragma unroll
        for (int nt = 0; nt < 4; ++nt) {
            pl += cr[nt][i] * alv[nt];
            pr += cr[nt][i] * arv[nt];
        }
#pragma unroll
        for (int o = 1; o < 16; o <<= 1) {
            pl += __shfl_xor(pl, o, 64);
            pr += __shfl_xor(pr, o, 64);
        }
        int r = r0 + i;
        if ((lane & 15) == 0 && r < M) {
            el[(size_t)r * H + head] = pl;
            er[(size_t)r * H + head] = pr;
        }
    }
}

// ---------------- layer-1 edges: block per dst, wave = head, 8x8 lane layout ----------------
// lane = eg*8 + d8: group eg handles edges 8i+eg; lane covers dims [d8*8, d8*8+8) (16B loads).
__global__ __launch_bounds__(256) void k_edge1(const int* __restrict__ offs,
                        const int* __restrict__ csr_src,
                        const float* __restrict__ el, const float* __restrict__ er,
                        const unsigned short* __restrict__ feat,
                        const unsigned short* __restrict__ b1,
                        unsigned short* __restrict__ h1) {
    int node = blockIdx.x;
    int head = threadIdx.x >> 6, lane = threadIdx.x & 63;
    int eg = lane >> 3, d8 = lane & 7;
    int start = offs[node], end = offs[node + 1];
    float er_d = er[node * NH + head];
    float lsum = 0.f;
    float a[8] = {};
    for (int base = start; base < end; base += 64) {
        int c = base + lane;
        float wgt = 0.f; int s = 0;
        if (c < end) {
            s = csr_src[c];
            float x = el[s * NH + head] + er_d;
            x = (x >= 0.f) ? x : 0.2f * x;
            wgt = __expf(x);       // |x| ~ O(1): shift-free softmax (shift-invariant)
        }
        lsum += wgt;
        int cnt = end - base; if (cnt > 64) cnt = 64;
        int niter = (cnt + 7) >> 3;
#pragma unroll 2
        for (int i = 0; i < niter; ++i) {
            int idx = 8 * i + eg;
            float we = __shfl(wgt, idx, 64);
            int   se = __shfl(s, idx, 64);
            u16x8 fv = *(const u16x8*)&feat[(((size_t)se * NH + head) << 6) + (d8 << 3)];
#pragma unroll
            for (int j = 0; j < 8; ++j) a[j] += we * b2f(fv[j]);
        }
    }
#pragma unroll
    for (int o = 1; o < 64; o <<= 1) lsum += __shfl_xor(lsum, o, 64);
#pragma unroll
    for (int j = 0; j < 8; ++j) {
        a[j] += __shfl_xor(a[j], 8, 64);
        a[j] += __shfl_xor(a[j], 16, 64);
        a[j] += __shfl_xor(a[j], 32, 64);
    }
    if (eg == 0) {
        float inv = (lsum > 0.f) ? 1.f / lsum : 0.f;
        u16x8 r;
#pragma unroll
        for (int j = 0; j < 8; ++j) {
            float o = a[j] * inv + b2f(b1[head * 64 + d8 * 8 + j]);
            o = (o > 0.f) ? o : (__expf(o) - 1.f);   // ELU
            r[j] = f2b(o);
        }
        *(u16x8*)&h1[(((size_t)node * NH + head) << 6) + d8 * 8] = r;
    }
}

// ---------------- layer-2 edges: wave per dst (H=1, D=64), 8x8 layout ----------------
__global__ __launch_bounds__(256) void k_edge2(const int* __restrict__ offs,
                        const int* __restrict__ csr_src,
                        const float* __restrict__ el, const float* __restrict__ er,
                        const unsigned short* __restrict__ feat,
                        const unsigned short* __restrict__ b2,
                        void* __restrict__ out, const int* __restrict__ flagp) {
    int wave = threadIdx.x >> 6, lane = threadIdx.x & 63;
    int node = blockIdx.x * 4 + wave;
    if (node >= NN) return;
    int eg = lane >> 3, d8 = lane & 7;
    int isbf = flagp[0];
    int start = offs[node], end = offs[node + 1];
    float er_d = er[node];
    float lsum = 0.f;
    float a[8] = {};
    for (int base = start; base < end; base += 64) {
        int c = base + lane;
        float wgt = 0.f; int s = 0;
        if (c < end) {
            s = csr_src[c];
            float x = el[s] + er_d;
            x = (x >= 0.f) ? x : 0.2f * x;
            wgt = __expf(x);
        }
        lsum += wgt;
        int cnt = end - base; if (cnt > 64) cnt = 64;
        int niter = (cnt + 7) >> 3;
#pragma unroll 2
        for (int i = 0; i < niter; ++i) {
            int idx = 8 * i + eg;
            float we = __shfl(wgt, idx, 64);
            int   se = __shfl(s, idx, 64);
            u16x8 fv = *(const u16x8*)&feat[((size_t)se << 6) + (d8 << 3)];
#pragma unroll
            for (int j = 0; j < 8; ++j) a[j] += we * b2f(fv[j]);
        }
    }
#pragma unroll
    for (int o = 1; o < 64; o <<= 1) lsum += __shfl_xor(lsum, o, 64);
#pragma unroll
    for (int j = 0; j < 8; ++j) {
        a[j] += __shfl_xor(a[j], 8, 64);
        a[j] += __shfl_xor(a[j], 16, 64);
        a[j] += __shfl_xor(a[j], 32, 64);
    }
    if (eg == 0) {
        float inv = (lsum > 0.f) ? 1.f / lsum : 0.f;
        float o[8];
#pragma unroll
        for (int j = 0; j < 8; ++j) o[j] = a[j] * inv + b2f(b2[d8 * 8 + j]);
        size_t ob = ((size_t)node << 6) + d8 * 8;
        if (isbf) {
            u16x8 r;
#pragma unroll
            for (int j = 0; j < 8; ++j) r[j] = f2b(o[j]);
            *(u16x8*)&((unsigned short*)out)[ob] = r;
        } else {
            float4 r0, r1;
            r0.x = o[0]; r0.y = o[1]; r0.z = o[2]; r0.w = o[3];
            r1.x = o[4]; r1.y = o[5]; r1.z = o[6]; r1.w = o[7];
            *(float4*)&((float*)out)[ob] = r0;
            *(float4*)&((float*)out)[ob + 4] = r1;
        }
    }
}

extern "C" void kernel_launch(void* const* d_in, const int* in_sizes, int n_in,
                              void* d_out, int out_size, void* d_ws, size_t ws_size,
                              hipStream_t stream) {
    const void* h   = d_in[0];
    const int*  src = (const int*)d_in[1];
    const int*  dst = (const int*)d_in[2];
    const void* W1  = d_in[3];
    const void* al1 = d_in[4];
    const void* ar1 = d_in[5];
    const void* b1  = d_in[6];
    const void* W2  = d_in[7];
    const void* al2 = d_in[8];
    const void* ar2 = d_in[9];
    const void* b2  = d_in[10];

    char* w = (char*)d_ws;
    size_t off = 0;
    auto alloc = [&](size_t bytes) -> void* {
        void* p = w + off;
        off = (off + bytes + 255) & ~(size_t)255;
        return p;
    };
    int* flag               = (int*)alloc(4);
    int* deg                = (int*)alloc(NN * 4);
    int* cursor             = (int*)alloc(NN * 4);
    int* offs               = (int*)alloc((NN + 1) * 4);
    int* csr_src            = (int*)alloc(NE * 4);
    unsigned short* canon   = (unsigned short*)alloc(960 * 2);
    unsigned short* W1T     = (unsigned short*)alloc(256 * 256 * 2);
    unsigned short* W2T     = (unsigned short*)alloc(64 * 256 * 2);
    unsigned short* feat1   = (unsigned short*)alloc((size_t)NN * 256 * 2);
    float* el1              = (float*)alloc(NN * NH * 4);
    float* er1              = (float*)alloc(NN * NH * 4);
    unsigned short* h1      = (unsigned short*)alloc((size_t)NN * 256 * 2);
    unsigned short* feat2   = (unsigned short*)alloc((size_t)NN * 64 * 2);
    float* el2              = (float*)alloc(NN * 4);
    float* er2              = (float*)alloc(NN * 4);
    (void)ws_size; (void)in_sizes; (void)n_in; (void)out_size;

    unsigned short* cal1 = canon + 0;
    unsigned short* car1 = canon + 256;
    unsigned short* cb1  = canon + 512;
    unsigned short* cal2 = canon + 768;
    unsigned short* car2 = canon + 832;
    unsigned short* cb2  = canon + 896;

    // 1: prep (flag + canon + transposes + deg zero)
    k_prep<<<363, 256, 0, stream>>>((const unsigned short*)h, W1, W2,
                                    al1, ar1, b1, al2, ar2, b2,
                                    W1T, W2T, canon, deg, flag);
    // 2-4: CSR
    k_deg<<<(NE + 255) / 256, 256, 0, stream>>>(dst, deg, NE);
    k_scan<<<1, 256, 0, stream>>>(deg, offs, cursor, NN);
    k_scatter<<<(NE + 255) / 256, 256, 0, stream>>>(src, dst, cursor, csr_src, NE);

    // 5-6: layer 1
    k_gemm<<<dim3((NN + 63) / 64, 4), 256, 0, stream>>>(h, W1T, feat1, el1, er1,
                                                        cal1, car1, NN, 256, NH, flag);
    k_edge1<<<NN, 256, 0, stream>>>(offs, csr_src, el1, er1, feat1, cb1, h1);

    // 7-8: layer 2 (h1 is known-bf16 -> flagp=nullptr)
    k_gemm<<<dim3((NN + 63) / 64, 1), 256, 0, stream>>>(h1, W2T, feat2, el2, er2,
                                                        cal2, car2, NN, 64, 1, nullptr);
    k_edge2<<<(NN + 3) / 4, 256, 0, stream>>>(offs, csr_src, el2, er2, feat2, cb2, d_out, flag);
}

// Round 6
// 206.929 us; speedup vs baseline: 1.0511x; 1.0511x over previous
//
#include <hip/hip_runtime.h>
#include <hip/hip_bf16.h>
#include <stdint.h>

#define NN 10000
#define NE 320000
#define NH 4

typedef __attribute__((ext_vector_type(8))) short s16x8;
typedef __attribute__((ext_vector_type(4))) float f32x4;
typedef __attribute__((ext_vector_type(8))) unsigned short u16x8;

static __device__ __forceinline__ float b2f(unsigned short u) {
    union { unsigned int i; float f; } x; x.i = ((unsigned int)u) << 16; return x.f;
}
static __device__ __forceinline__ unsigned short f2b(float f) {
    unsigned int u = __float_as_uint(f);
    unsigned int r = (u + 0x7fffu + ((u >> 16) & 1u)) >> 16;
    return (unsigned short)r;
}

// ---------------- fused prep: dtype flag + canon small tensors + W transposes + deg zero ----
__global__ __launch_bounds__(256) void k_prep(const unsigned short* __restrict__ hraw,
                        const void* __restrict__ W1, const void* __restrict__ W2,
                        const void* al1, const void* ar1, const void* b1,
                        const void* al2, const void* ar2, const void* b2,
                        unsigned short* __restrict__ W1T, unsigned short* __restrict__ W2T,
                        unsigned short* __restrict__ canon, int* __restrict__ deg,
                        int* __restrict__ flag) {
    __shared__ int sb[256];
    int t = threadIdx.x;
    int cnt = 0;
    for (int i = t; i < 8192; i += 256) {
        unsigned short u = hraw[i];
        int e = (u >> 7) & 0xFF;
        cnt += (e >= 97 && e <= 157) ? 1 : 0;   // |x| in [2^-30, 2^30]
    }
    sb[t] = cnt;
    __syncthreads();
    for (int o = 128; o > 0; o >>= 1) {
        if (t < o) sb[t] += sb[t + o];
        __syncthreads();
    }
    int isbf = (sb[0] >= 6963) ? 1 : 0;         // 85% of 8192

    int idx = blockIdx.x * 256 + t;
    if (idx < 65536) {                           // W1T[n*256+k] = W1[k*256+n]
        int n = idx >> 8, k = idx & 255;
        W1T[idx] = isbf ? ((const unsigned short*)W1)[k * 256 + n]
                        : f2b(((const float*)W1)[k * 256 + n]);
    } else if (idx < 81920) {                    // W2T[n*256+k] = W2[k*64+n]
        int j = idx - 65536;
        int n = j >> 8, k = j & 255;
        W2T[j] = isbf ? ((const unsigned short*)W2)[k * 64 + n]
                      : f2b(((const float*)W2)[k * 64 + n]);
    } else if (idx < 82880) {                    // small tensors -> canon
        int j = idx - 81920;
        const void* srcp; int q;
        if      (j < 256) { srcp = al1; q = j; }
        else if (j < 512) { srcp = ar1; q = j - 256; }
        else if (j < 768) { srcp = b1;  q = j - 512; }
        else if (j < 832) { srcp = al2; q = j - 768; }
        else if (j < 896) { srcp = ar2; q = j - 832; }
        else              { srcp = b2;  q = j - 896; }
        canon[j] = isbf ? ((const unsigned short*)srcp)[q] : f2b(((const float*)srcp)[q]);
    } else if (idx < 92880) {                    // zero deg[10000]
        deg[idx - 82880] = 0;
    } else if (idx == 92880) {
        flag[0] = isbf;
    }
}

// ---------------- CSR build ----------------
__global__ void k_deg(const int* __restrict__ dst, int* __restrict__ deg, int e) {
    int i = blockIdx.x * 256 + threadIdx.x;
    if (i < e) atomicAdd(&deg[dst[i]], 1);
}

// single block, 256 threads, 40 contiguous elements per thread (256*40 >= NN)
__global__ void k_scan(const int* __restrict__ deg, int* __restrict__ offs,
                       int* __restrict__ cursor, int n) {
    __shared__ int wtot[4];
    int t = threadIdx.x;
    int lane = t & 63, wv = t >> 6;
    int base = t * 40;
    int sum = 0;
#pragma unroll
    for (int j = 0; j < 40; ++j) {
        int i = base + j;
        sum += (i < n) ? deg[i] : 0;
    }
    int x = sum;
    for (int o = 1; o < 64; o <<= 1) {
        int y = __shfl_up(x, o, 64);
        if (lane >= o) x += y;
    }
    if (lane == 63) wtot[wv] = x;
    __syncthreads();
    int wbase = 0;
    for (int k = 0; k < wv; ++k) wbase += wtot[k];
    int run = wbase + x - sum;
    for (int j = 0; j < 40; ++j) {
        int i = base + j;
        if (i < n) {
            offs[i] = run;
            cursor[i] = run;
            run += deg[i];
        }
    }
    if (t == 255) offs[n] = run;
}

__global__ void k_scatter(const int* __restrict__ src, const int* __restrict__ dst,
                          int* __restrict__ cursor, int* __restrict__ csr_src, int e) {
    int i = blockIdx.x * 256 + threadIdx.x;
    if (i < e) {
        int slot = atomicAdd(&cursor[dst[i]], 1);
        csr_src[slot] = src[i];
    }
}

// ---------------- bf16 MFMA GEMM: one-time LDS B-stage, barrier-free K-loop ----------------
// C[M, H*64] = A[M,256] @ B; BT is [H*64, 256] bf16. Grid (ceil(M/64), H), 4 waves.
// B-tile (this head's 64 rows x 256 k = 32KB) staged to LDS once; A direct 16B global loads.
#define BSTRIDE 264   // shorts; 528B row: 16B-aligned, bank rotation 4r mod 32
__global__ __launch_bounds__(256) void k_gemm(const void* __restrict__ A,
                                              const unsigned short* __restrict__ BT,
                                              unsigned short* __restrict__ C,
                                              float* __restrict__ el, float* __restrict__ er,
                                              const unsigned short* __restrict__ al,
                                              const unsigned short* __restrict__ ar,
                                              int M, int N, int H,
                                              const int* __restrict__ flagp) {
    __shared__ short Bs[64 * BSTRIDE];
    int t = threadIdx.x;
    int wave = t >> 6, lane = t & 63;
    int head = blockIdx.y;
    int m0 = blockIdx.x * 64;
    const unsigned short* Bh = BT + (size_t)head * 64 * 256;

    // stage B: 64 rows x 256 shorts = 2048 x 16B chunks; 8 chunks per thread
#pragma unroll
    for (int i = 0; i < 8; ++i) {
        int idx = t + i * 256;              // chunk index
        int row = idx >> 5, chunk = idx & 31;
        *(s16x8*)&Bs[row * BSTRIDE + chunk * 8] =
            *(const s16x8*)&Bh[(size_t)row * 256 + chunk * 8];
    }
    __syncthreads();

    int aRow = m0 + wave * 16 + (lane & 15);
    int aR = (aRow < M) ? aRow : M - 1;          // clamp loads; stores guarded
    int kq = (lane >> 4) * 8;
    int a_isbf = flagp ? flagp[0] : 1;
    const unsigned short* Ab = (const unsigned short*)A;
    const float*          Af = (const float*)A;
    f32x4 acc[4] = {};

#pragma unroll
    for (int k0 = 0; k0 < 256; k0 += 32) {
        s16x8 afr;
        if (a_isbf) {
            afr = *(const s16x8*)&Ab[(size_t)aR * 256 + k0 + kq];
        } else {
            const float* pf = &Af[(size_t)aR * 256 + k0 + kq];
            float4 x0 = *(const float4*)pf;
            float4 x1 = *(const float4*)(pf + 4);
            afr[0] = (short)f2b(x0.x); afr[1] = (short)f2b(x0.y);
            afr[2] = (short)f2b(x0.z); afr[3] = (short)f2b(x0.w);
            afr[4] = (short)f2b(x1.x); afr[5] = (short)f2b(x1.y);
            afr[6] = (short)f2b(x1.z); afr[7] = (short)f2b(x1.w);
        }
#pragma unroll
        for (int nt = 0; nt < 4; ++nt) {
            s16x8 bfr = *(const s16x8*)&Bs[(nt * 16 + (lane & 15)) * BSTRIDE + k0 + kq];
            acc[nt] = __builtin_amdgcn_mfma_f32_16x16x32_bf16(afr, bfr, acc[nt], 0, 0, 0);
        }
    }

    // C store (bf16); keep rounded values so el/er match what edge kernels re-read
    int col0 = head * 64 + (lane & 15);
    int r0 = m0 + wave * 16 + (lane >> 4) * 4;
    float cr[4][4];
#pragma unroll
    for (int nt = 0; nt < 4; ++nt) {
        int col = col0 + nt * 16;
#pragma unroll
        for (int i = 0; i < 4; ++i) {
            unsigned short cb = f2b(acc[nt][i]);
            cr[nt][i] = b2f(cb);
            int r = r0 + i;
            if (r < M) C[(size_t)r * N + col] = cb;
        }
    }

    float alv[4], arv[4];
#pragma unroll
    for (int nt = 0; nt < 4; ++nt) {
        int c = (lane & 15) + nt * 16;
        alv[nt] = b2f(al[head * 64 + c]);
        arv[nt] = b2f(ar[head * 64 + c]);
    }
#pragma unroll
    for (int i = 0; i < 4; ++i) {
        float pl = 0.f, pr = 0.f;
#pragma unroll
        for (int nt = 0; nt < 4; ++nt) {
            pl += cr[nt][i] * alv[nt];
            pr += cr[nt][i] * arv[nt];
        }
#pragma unroll
        for (int o = 1; o < 16; o <<= 1) {
            pl += __shfl_xor(pl, o, 64);
            pr += __shfl_xor(pr, o, 64);
        }
        int r = r0 + i;
        if ((lane & 15) == 0 && r < M) {
            el[(size_t)r * H + head] = pl;
            er[(size_t)r * H + head] = pr;
        }
    }
}

// ---------------- layer-1 edges: block per dst, wave = head, 8x8 lane layout ----------------
__global__ __launch_bounds__(256) void k_edge1(const int* __restrict__ offs,
                        const int* __restrict__ csr_src,
                        const float* __restrict__ el, const float* __restrict__ er,
                        const unsigned short* __restrict__ feat,
                        const unsigned short* __restrict__ b1,
                        unsigned short* __restrict__ h1) {
    int node = blockIdx.x;
    int head = threadIdx.x >> 6, lane = threadIdx.x & 63;
    int eg = lane >> 3, d8 = lane & 7;
    int start = offs[node], end = offs[node + 1];
    float er_d = er[node * NH + head];
    float lsum = 0.f;
    float a[8] = {};
    for (int base = start; base < end; base += 64) {
        int c = base + lane;
        float wgt = 0.f; int s = 0;
        if (c < end) {
            s = csr_src[c];
            float x = el[s * NH + head] + er_d;
            x = (x >= 0.f) ? x : 0.2f * x;
            wgt = __expf(x);       // |x| ~ O(1): shift-free softmax (shift-invariant)
        }
        lsum += wgt;
        int cnt = end - base; if (cnt > 64) cnt = 64;
        int niter = (cnt + 7) >> 3;
#pragma unroll 2
        for (int i = 0; i < niter; ++i) {
            int idx = 8 * i + eg;
            float we = __shfl(wgt, idx, 64);
            int   se = __shfl(s, idx, 64);
            u16x8 fv = *(const u16x8*)&feat[(((size_t)se * NH + head) << 6) + (d8 << 3)];
#pragma unroll
            for (int j = 0; j < 8; ++j) a[j] += we * b2f(fv[j]);
        }
    }
#pragma unroll
    for (int o = 1; o < 64; o <<= 1) lsum += __shfl_xor(lsum, o, 64);
#pragma unroll
    for (int j = 0; j < 8; ++j) {
        a[j] += __shfl_xor(a[j], 8, 64);
        a[j] += __shfl_xor(a[j], 16, 64);
        a[j] += __shfl_xor(a[j], 32, 64);
    }
    if (eg == 0) {
        float inv = (lsum > 0.f) ? 1.f / lsum : 0.f;
        u16x8 r;
#pragma unroll
        for (int j = 0; j < 8; ++j) {
            float o = a[j] * inv + b2f(b1[head * 64 + d8 * 8 + j]);
            o = (o > 0.f) ? o : (__expf(o) - 1.f);   // ELU
            r[j] = f2b(o);
        }
        *(u16x8*)&h1[(((size_t)node * NH + head) << 6) + d8 * 8] = r;
    }
}

// ---------------- layer-2 edges: wave per dst (H=1, D=64), 8x8 layout ----------------
__global__ __launch_bounds__(256) void k_edge2(const int* __restrict__ offs,
                        const int* __restrict__ csr_src,
                        const float* __restrict__ el, const float* __restrict__ er,
                        const unsigned short* __restrict__ feat,
                        const unsigned short* __restrict__ b2,
                        void* __restrict__ out, const int* __restrict__ flagp) {
    int wave = threadIdx.x >> 6, lane = threadIdx.x & 63;
    int node = blockIdx.x * 4 + wave;
    if (node >= NN) return;
    int eg = lane >> 3, d8 = lane & 7;
    int isbf = flagp[0];
    int start = offs[node], end = offs[node + 1];
    float er_d = er[node];
    float lsum = 0.f;
    float a[8] = {};
    for (int base = start; base < end; base += 64) {
        int c = base + lane;
        float wgt = 0.f; int s = 0;
        if (c < end) {
            s = csr_src[c];
            float x = el[s] + er_d;
            x = (x >= 0.f) ? x : 0.2f * x;
            wgt = __expf(x);
        }
        lsum += wgt;
        int cnt = end - base; if (cnt > 64) cnt = 64;
        int niter = (cnt + 7) >> 3;
#pragma unroll 2
        for (int i = 0; i < niter; ++i) {
            int idx = 8 * i + eg;
            float we = __shfl(wgt, idx, 64);
            int   se = __shfl(s, idx, 64);
            u16x8 fv = *(const u16x8*)&feat[((size_t)se << 6) + (d8 << 3)];
#pragma unroll
            for (int j = 0; j < 8; ++j) a[j] += we * b2f(fv[j]);
        }
    }
#pragma unroll
    for (int o = 1; o < 64; o <<= 1) lsum += __shfl_xor(lsum, o, 64);
#pragma unroll
    for (int j = 0; j < 8; ++j) {
        a[j] += __shfl_xor(a[j], 8, 64);
        a[j] += __shfl_xor(a[j], 16, 64);
        a[j] += __shfl_xor(a[j], 32, 64);
    }
    if (eg == 0) {
        float inv = (lsum > 0.f) ? 1.f / lsum : 0.f;
        float o[8];
#pragma unroll
        for (int j = 0; j < 8; ++j) o[j] = a[j] * inv + b2f(b2[d8 * 8 + j]);
        size_t ob = ((size_t)node << 6) + d8 * 8;
        if (isbf) {
            u16x8 r;
#pragma unroll
            for (int j = 0; j < 8; ++j) r[j] = f2b(o[j]);
            *(u16x8*)&((unsigned short*)out)[ob] = r;
        } else {
            float4 r0, r1;
            r0.x = o[0]; r0.y = o[1]; r0.z = o[2]; r0.w = o[3];
            r1.x = o[4]; r1.y = o[5]; r1.z = o[6]; r1.w = o[7];
            *(float4*)&((float*)out)[ob] = r0;
            *(float4*)&((float*)out)[ob + 4] = r1;
        }
    }
}

extern "C" void kernel_launch(void* const* d_in, const int* in_sizes, int n_in,
                              void* d_out, int out_size, void* d_ws, size_t ws_size,
                              hipStream_t stream) {
    const void* h   = d_in[0];
    const int*  src = (const int*)d_in[1];
    const int*  dst = (const int*)d_in[2];
    const void* W1  = d_in[3];
    const void* al1 = d_in[4];
    const void* ar1 = d_in[5];
    const void* b1  = d_in[6];
    const void* W2  = d_in[7];
    const void* al2 = d_in[8];
    const void* ar2 = d_in[9];
    const void* b2  = d_in[10];

    char* w = (char*)d_ws;
    size_t off = 0;
    auto alloc = [&](size_t bytes) -> void* {
        void* p = w + off;
        off = (off + bytes + 255) & ~(size_t)255;
        return p;
    };
    int* flag               = (int*)alloc(4);
    int* deg                = (int*)alloc(NN * 4);
    int* cursor             = (int*)alloc(NN * 4);
    int* offs               = (int*)alloc((NN + 1) * 4);
    int* csr_src            = (int*)alloc(NE * 4);
    unsigned short* canon   = (unsigned short*)alloc(960 * 2);
    unsigned short* W1T     = (unsigned short*)alloc(256 * 256 * 2);
    unsigned short* W2T     = (unsigned short*)alloc(64 * 256 * 2);
    unsigned short* feat1   = (unsigned short*)alloc((size_t)NN * 256 * 2);
    float* el1              = (float*)alloc(NN * NH * 4);
    float* er1              = (float*)alloc(NN * NH * 4);
    unsigned short* h1      = (unsigned short*)alloc((size_t)NN * 256 * 2);
    unsigned short* feat2   = (unsigned short*)alloc((size_t)NN * 64 * 2);
    float* el2              = (float*)alloc(NN * 4);
    float* er2              = (float*)alloc(NN * 4);
    (void)ws_size; (void)in_sizes; (void)n_in; (void)out_size;

    unsigned short* cal1 = canon + 0;
    unsigned short* car1 = canon + 256;
    unsigned short* cb1  = canon + 512;
    unsigned short* cal2 = canon + 768;
    unsigned short* car2 = canon + 832;
    unsigned short* cb2  = canon + 896;

    // 1: prep (flag + canon + transposes + deg zero)
    k_prep<<<363, 256, 0, stream>>>((const unsigned short*)h, W1, W2,
                                    al1, ar1, b1, al2, ar2, b2,
                                    W1T, W2T, canon, deg, flag);
    // 2-4: CSR
    k_deg<<<(NE + 255) / 256, 256, 0, stream>>>(dst, deg, NE);
    k_scan<<<1, 256, 0, stream>>>(deg, offs, cursor, NN);
    k_scatter<<<(NE + 255) / 256, 256, 0, stream>>>(src, dst, cursor, csr_src, NE);

    // 5-6: layer 1
    k_gemm<<<dim3((NN + 63) / 64, 4), 256, 0, stream>>>(h, W1T, feat1, el1, er1,
                                                        cal1, car1, NN, 256, NH, flag);
    k_edge1<<<NN, 256, 0, stream>>>(offs, csr_src, el1, er1, feat1, cb1, h1);

    // 7-8: layer 2 (h1 known-bf16 -> flagp=nullptr)
    k_gemm<<<dim3((NN + 63) / 64, 1), 256, 0, stream>>>(h1, W2T, feat2, el2, er2,
                                                        cal2, car2, NN, 64, 1, nullptr);
    k_edge2<<<(NN + 3) / 4, 256, 0, stream>>>(offs, csr_src, el2, er2, feat2, cb2, d_out, flag);
}

// Round 7
// 188.752 us; speedup vs baseline: 1.1523x; 1.0963x over previous
//
#include <hip/hip_runtime.h>
#include <hip/hip_bf16.h>
#include <stdint.h>

#define NN 10000
#define NE 320000
#define NH 4

typedef __attribute__((ext_vector_type(8))) short s16x8;
typedef __attribute__((ext_vector_type(4))) float f32x4;
typedef __attribute__((ext_vector_type(8))) unsigned short u16x8;

static __device__ __forceinline__ float b2f(unsigned short u) {
    union { unsigned int i; float f; } x; x.i = ((unsigned int)u) << 16; return x.f;
}
static __device__ __forceinline__ unsigned short f2b(float f) {
    unsigned int u = __float_as_uint(f);
    unsigned int r = (u + 0x7fffu + ((u >> 16) & 1u)) >> 16;
    return (unsigned short)r;
}

// ---------------- fused prep: dtype flag + canon small tensors + W transposes + deg zero ----
__global__ __launch_bounds__(256) void k_prep(const unsigned short* __restrict__ hraw,
                        const void* __restrict__ W1, const void* __restrict__ W2,
                        const void* al1, const void* ar1, const void* b1,
                        const void* al2, const void* ar2, const void* b2,
                        unsigned short* __restrict__ W1T, unsigned short* __restrict__ W2T,
                        unsigned short* __restrict__ canon, int* __restrict__ deg,
                        int* __restrict__ flag) {
    __shared__ int sb[256];
    int t = threadIdx.x;
    int cnt = 0;
    for (int i = t; i < 2048; i += 256) {       // 2048 samples: >20 sigma margin
        unsigned short u = hraw[i];
        int e = (u >> 7) & 0xFF;
        cnt += (e >= 97 && e <= 157) ? 1 : 0;   // |x| in [2^-30, 2^30]
    }
    sb[t] = cnt;
    __syncthreads();
    for (int o = 128; o > 0; o >>= 1) {
        if (t < o) sb[t] += sb[t + o];
        __syncthreads();
    }
    int isbf = (sb[0] >= 1741) ? 1 : 0;         // 85% of 2048

    int idx = blockIdx.x * 256 + t;
    if (idx < 65536) {                           // W1T[n*256+k] = W1[k*256+n]
        int n = idx >> 8, k = idx & 255;
        W1T[idx] = isbf ? ((const unsigned short*)W1)[k * 256 + n]
                        : f2b(((const float*)W1)[k * 256 + n]);
    } else if (idx < 81920) {                    // W2T[n*256+k] = W2[k*64+n]
        int j = idx - 65536;
        int n = j >> 8, k = j & 255;
        W2T[j] = isbf ? ((const unsigned short*)W2)[k * 64 + n]
                      : f2b(((const float*)W2)[k * 64 + n]);
    } else if (idx < 82880) {                    // small tensors -> canon
        int j = idx - 81920;
        const void* srcp; int q;
        if      (j < 256) { srcp = al1; q = j; }
        else if (j < 512) { srcp = ar1; q = j - 256; }
        else if (j < 768) { srcp = b1;  q = j - 512; }
        else if (j < 832) { srcp = al2; q = j - 768; }
        else if (j < 896) { srcp = ar2; q = j - 832; }
        else              { srcp = b2;  q = j - 896; }
        canon[j] = isbf ? ((const unsigned short*)srcp)[q] : f2b(((const float*)srcp)[q]);
    } else if (idx < 92880) {                    // zero deg[10000]
        deg[idx - 82880] = 0;
    } else if (idx == 92880) {
        flag[0] = isbf;
    }
}

// ---------------- CSR build ----------------
__global__ void k_deg(const int* __restrict__ dst, int* __restrict__ deg, int e) {
    int i = blockIdx.x * 256 + threadIdx.x;
    if (i < e) atomicAdd(&deg[dst[i]], 1);
}

// single block, 256 threads, 40 contiguous elements per thread, register-resident
__global__ void k_scan(const int* __restrict__ deg, int* __restrict__ offs,
                       int* __restrict__ cursor, int n) {
    __shared__ int wtot[4];
    int t = threadIdx.x;
    int lane = t & 63, wv = t >> 6;
    int base = t * 40;
    int d[40];
#pragma unroll
    for (int j = 0; j < 10; ++j) {               // int4 loads (deg buffer is 256B-aligned;
        int4 v = *(const int4*)&deg[base + j * 4];  // tail reads stay inside ws)
        d[j * 4 + 0] = v.x; d[j * 4 + 1] = v.y;
        d[j * 4 + 2] = v.z; d[j * 4 + 3] = v.w;
    }
    int sum = 0;
#pragma unroll
    for (int j = 0; j < 40; ++j) sum += (base + j < n) ? d[j] : 0;
    int x = sum;
    for (int o = 1; o < 64; o <<= 1) {
        int y = __shfl_up(x, o, 64);
        if (lane >= o) x += y;
    }
    if (lane == 63) wtot[wv] = x;
    __syncthreads();
    int wbase = 0;
    for (int k = 0; k < wv; ++k) wbase += wtot[k];
    int run = wbase + x - sum;
    int r[40];
#pragma unroll
    for (int j = 0; j < 40; ++j) {
        r[j] = run;
        run += (base + j < n) ? d[j] : 0;
    }
    if (base + 39 < n) {
#pragma unroll
        for (int j = 0; j < 10; ++j) {
            int4 v; v.x = r[j*4]; v.y = r[j*4+1]; v.z = r[j*4+2]; v.w = r[j*4+3];
            *(int4*)&offs[base + j * 4] = v;
            *(int4*)&cursor[base + j * 4] = v;
        }
    } else {
        for (int j = 0; j < 40; ++j) {
            if (base + j < n) { offs[base + j] = r[j]; cursor[base + j] = r[j]; }
        }
    }
    if (t == 255) offs[n] = run;
}

__global__ void k_scatter(const int* __restrict__ src, const int* __restrict__ dst,
                          int* __restrict__ cursor, int* __restrict__ csr_src, int e) {
    int i = blockIdx.x * 256 + threadIdx.x;
    if (i < e) {
        int slot = atomicAdd(&cursor[dst[i]], 1);
        csr_src[slot] = src[i];
    }
}

// ---------------- bf16 MFMA GEMM: one-time LDS B-stage, 128 rows/block, barrier-free K-loop ----
// C[M, H*64] = A[M,256] @ B; BT is [H*64, 256] bf16. Grid (ceil(M/128), H), 4 waves.
#define BSTRIDE 264   // shorts; 528B row: 16B-aligned, bank rotation 4r mod 32
__global__ __launch_bounds__(256) void k_gemm(const void* __restrict__ A,
                                              const unsigned short* __restrict__ BT,
                                              unsigned short* __restrict__ C,
                                              float* __restrict__ el, float* __restrict__ er,
                                              const unsigned short* __restrict__ al,
                                              const unsigned short* __restrict__ ar,
                                              int M, int N, int H,
                                              const int* __restrict__ flagp) {
    __shared__ short Bs[64 * BSTRIDE];
    int t = threadIdx.x;
    int wave = t >> 6, lane = t & 63;
    int head = blockIdx.y;
    int m0 = blockIdx.x * 128;
    const unsigned short* Bh = BT + (size_t)head * 64 * 256;

    // stage B: 64 rows x 256 shorts = 2048 x 16B chunks; 8 chunks/thread
#pragma unroll
    for (int i = 0; i < 8; ++i) {
        int idx = t + i * 256;
        int row = idx >> 5, chunk = idx & 31;
        *(s16x8*)&Bs[row * BSTRIDE + chunk * 8] =
            *(const s16x8*)&Bh[(size_t)row * 256 + chunk * 8];
    }
    __syncthreads();

    int kq = (lane >> 4) * 8;
    int a_isbf = flagp ? flagp[0] : 1;
    const unsigned short* Ab = (const unsigned short*)A;
    const float*          Af = (const float*)A;
    int aR[2];
#pragma unroll
    for (int mi = 0; mi < 2; ++mi) {
        int aRow = m0 + mi * 64 + wave * 16 + (lane & 15);
        aR[mi] = (aRow < M) ? aRow : M - 1;      // clamp loads; stores guarded
    }
    f32x4 acc[2][4] = {};

#pragma unroll
    for (int k0 = 0; k0 < 256; k0 += 32) {
        s16x8 afr[2];
#pragma unroll
        for (int mi = 0; mi < 2; ++mi) {
            if (a_isbf) {
                afr[mi] = *(const s16x8*)&Ab[(size_t)aR[mi] * 256 + k0 + kq];
            } else {
                const float* pf = &Af[(size_t)aR[mi] * 256 + k0 + kq];
                float4 x0 = *(const float4*)pf;
                float4 x1 = *(const float4*)(pf + 4);
                afr[mi][0] = (short)f2b(x0.x); afr[mi][1] = (short)f2b(x0.y);
                afr[mi][2] = (short)f2b(x0.z); afr[mi][3] = (short)f2b(x0.w);
                afr[mi][4] = (short)f2b(x1.x); afr[mi][5] = (short)f2b(x1.y);
                afr[mi][6] = (short)f2b(x1.z); afr[mi][7] = (short)f2b(x1.w);
            }
        }
#pragma unroll
        for (int nt = 0; nt < 4; ++nt) {
            s16x8 bfr = *(const s16x8*)&Bs[(nt * 16 + (lane & 15)) * BSTRIDE + k0 + kq];
            acc[0][nt] = __builtin_amdgcn_mfma_f32_16x16x32_bf16(afr[0], bfr, acc[0][nt], 0, 0, 0);
            acc[1][nt] = __builtin_amdgcn_mfma_f32_16x16x32_bf16(afr[1], bfr, acc[1][nt], 0, 0, 0);
        }
    }

    float alv[4], arv[4];
#pragma unroll
    for (int nt = 0; nt < 4; ++nt) {
        int c = (lane & 15) + nt * 16;
        alv[nt] = b2f(al[head * 64 + c]);
        arv[nt] = b2f(ar[head * 64 + c]);
    }
    int col0 = head * 64 + (lane & 15);
#pragma unroll
    for (int mi = 0; mi < 2; ++mi) {
        int r0 = m0 + mi * 64 + wave * 16 + (lane >> 4) * 4;
        float cr[4][4];
#pragma unroll
        for (int nt = 0; nt < 4; ++nt) {
            int col = col0 + nt * 16;
#pragma unroll
            for (int i = 0; i < 4; ++i) {
                unsigned short cb = f2b(acc[mi][nt][i]);
                cr[nt][i] = b2f(cb);
                int r = r0 + i;
                if (r < M) C[(size_t)r * N + col] = cb;
            }
        }
#pragma unroll
        for (int i = 0; i < 4; ++i) {
            float pl = 0.f, pr = 0.f;
#pragma unroll
            for (int nt = 0; nt < 4; ++nt) {
                pl += cr[nt][i] * alv[nt];
                pr += cr[nt][i] * arv[nt];
            }
#pragma unroll
            for (int o = 1; o < 16; o <<= 1) {
                pl += __shfl_xor(pl, o, 64);
                pr += __shfl_xor(pr, o, 64);
            }
            int r = r0 + i;
            if ((lane & 15) == 0 && r < M) {
                el[(size_t)r * H + head] = pl;
                er[(size_t)r * H + head] = pr;
            }
        }
    }
}

// ---------------- layer-1 edges: block per dst; LDS weight phase + per-head aggregation ----
// Phase 1: threads t<cn compute all 4 head-weights of edge t (one float4 el gather, 4 exps)
// into LDS. Phase 2: wave=head, lanes 8 edge-groups x 8 dim-lanes; (s,w) via LDS broadcast.
__global__ __launch_bounds__(256) void k_edge1(const int* __restrict__ offs,
                        const int* __restrict__ csr_src,
                        const float* __restrict__ el, const float* __restrict__ er,
                        const unsigned short* __restrict__ feat,
                        const unsigned short* __restrict__ b1,
                        unsigned short* __restrict__ h1) {
    __shared__ int   s_s[128];
    __shared__ float s_w[128][4];
    int node = blockIdx.x;
    int t = threadIdx.x;
    int head = t >> 6, lane = t & 63;
    int eg = lane >> 3, d8 = lane & 7;
    int start = offs[node], end = offs[node + 1];
    float4 er4 = *(const float4*)&er[(size_t)node * 4];
    float lsum = 0.f;
    float a[8] = {};
    for (int cbase = start; cbase < end; cbase += 128) {
        int cn = end - cbase; if (cn > 128) cn = 128;
        __syncthreads();                          // protect LDS reuse across chunks
        if (t < cn) {
            int s = csr_src[cbase + t];
            s_s[t] = s;
            float4 el4 = *(const float4*)&el[(size_t)s * 4];
            float x0 = el4.x + er4.x; x0 = (x0 >= 0.f) ? x0 : 0.2f * x0;
            float x1 = el4.y + er4.y; x1 = (x1 >= 0.f) ? x1 : 0.2f * x1;
            float x2 = el4.z + er4.z; x2 = (x2 >= 0.f) ? x2 : 0.2f * x2;
            float x3 = el4.w + er4.w; x3 = (x3 >= 0.f) ? x3 : 0.2f * x3;
            s_w[t][0] = __expf(x0);               // |x| ~ O(1): shift-free softmax
            s_w[t][1] = __expf(x1);
            s_w[t][2] = __expf(x2);
            s_w[t][3] = __expf(x3);
        } else if (t < ((cn + 7) & ~7)) {         // zero tail so phase 2 is maskless
            s_s[t] = 0;
            s_w[t][0] = 0.f; s_w[t][1] = 0.f; s_w[t][2] = 0.f; s_w[t][3] = 0.f;
        }
        __syncthreads();
        int niter = (cn + 7) >> 3;                // idx = 8i+eg <= 127 always
#pragma unroll 2
        for (int i = 0; i < niter; ++i) {
            int idx = 8 * i + eg;
            float we = s_w[idx][head];
            int   se = s_s[idx];
            if (d8 == 0) lsum += we;
            u16x8 fv = *(const u16x8*)&feat[(((size_t)se * NH + head) << 6) + (d8 << 3)];
#pragma unroll
            for (int j = 0; j < 8; ++j) a[j] += we * b2f(fv[j]);
        }
    }
#pragma unroll
    for (int o = 1; o < 64; o <<= 1) lsum += __shfl_xor(lsum, o, 64);
#pragma unroll
    for (int j = 0; j < 8; ++j) {
        a[j] += __shfl_xor(a[j], 8, 64);
        a[j] += __shfl_xor(a[j], 16, 64);
        a[j] += __shfl_xor(a[j], 32, 64);
    }
    if (eg == 0) {
        float inv = (lsum > 0.f) ? 1.f / lsum : 0.f;
        u16x8 r;
#pragma unroll
        for (int j = 0; j < 8; ++j) {
            float o = a[j] * inv + b2f(b1[head * 64 + d8 * 8 + j]);
            o = (o > 0.f) ? o : (__expf(o) - 1.f);   // ELU
            r[j] = f2b(o);
        }
        *(u16x8*)&h1[(((size_t)node * NH + head) << 6) + d8 * 8] = r;
    }
}

// ---------------- layer-2 edges: wave per dst (H=1, D=64), 8x8 layout ----------------
__global__ __launch_bounds__(256) void k_edge2(const int* __restrict__ offs,
                        const int* __restrict__ csr_src,
                        const float* __restrict__ el, const float* __restrict__ er,
                        const unsigned short* __restrict__ feat,
                        const unsigned short* __restrict__ b2,
                        void* __restrict__ out, const int* __restrict__ flagp) {
    int wave = threadIdx.x >> 6, lane = threadIdx.x & 63;
    int node = blockIdx.x * 4 + wave;
    if (node >= NN) return;
    int eg = lane >> 3, d8 = lane & 7;
    int isbf = flagp[0];
    int start = offs[node], end = offs[node + 1];
    float er_d = er[node];
    float lsum = 0.f;
    float a[8] = {};
    for (int base = start; base < end; base += 64) {
        int c = base + lane;
        float wgt = 0.f; int s = 0;
        if (c < end) {
            s = csr_src[c];
            float x = el[s] + er_d;
            x = (x >= 0.f) ? x : 0.2f * x;
            wgt = __expf(x);
        }
        lsum += wgt;
        int cnt = end - base; if (cnt > 64) cnt = 64;
        int niter = (cnt + 7) >> 3;
#pragma unroll 2
        for (int i = 0; i < niter; ++i) {
            int idx = 8 * i + eg;
            float we = __shfl(wgt, idx, 64);
            int   se = __shfl(s, idx, 64);
            u16x8 fv = *(const u16x8*)&feat[((size_t)se << 6) + (d8 << 3)];
#pragma unroll
            for (int j = 0; j < 8; ++j) a[j] += we * b2f(fv[j]);
        }
    }
#pragma unroll
    for (int o = 1; o < 64; o <<= 1) lsum += __shfl_xor(lsum, o, 64);
#pragma unroll
    for (int j = 0; j < 8; ++j) {
        a[j] += __shfl_xor(a[j], 8, 64);
        a[j] += __shfl_xor(a[j], 16, 64);
        a[j] += __shfl_xor(a[j], 32, 64);
    }
    if (eg == 0) {
        float inv = (lsum > 0.f) ? 1.f / lsum : 0.f;
        float o[8];
#pragma unroll
        for (int j = 0; j < 8; ++j) o[j] = a[j] * inv + b2f(b2[d8 * 8 + j]);
        size_t ob = ((size_t)node << 6) + d8 * 8;
        if (isbf) {
            u16x8 r;
#pragma unroll
            for (int j = 0; j < 8; ++j) r[j] = f2b(o[j]);
            *(u16x8*)&((unsigned short*)out)[ob] = r;
        } else {
            float4 r0, r1;
            r0.x = o[0]; r0.y = o[1]; r0.z = o[2]; r0.w = o[3];
            r1.x = o[4]; r1.y = o[5]; r1.z = o[6]; r1.w = o[7];
            *(float4*)&((float*)out)[ob] = r0;
            *(float4*)&((float*)out)[ob + 4] = r1;
        }
    }
}

extern "C" void kernel_launch(void* const* d_in, const int* in_sizes, int n_in,
                              void* d_out, int out_size, void* d_ws, size_t ws_size,
                              hipStream_t stream) {
    const void* h   = d_in[0];
    const int*  src = (const int*)d_in[1];
    const int*  dst = (const int*)d_in[2];
    const void* W1  = d_in[3];
    const void* al1 = d_in[4];
    const void* ar1 = d_in[5];
    const void* b1  = d_in[6];
    const void* W2  = d_in[7];
    const void* al2 = d_in[8];
    const void* ar2 = d_in[9];
    const void* b2  = d_in[10];

    char* w = (char*)d_ws;
    size_t off = 0;
    auto alloc = [&](size_t bytes) -> void* {
        void* p = w + off;
        off = (off + bytes + 255) & ~(size_t)255;
        return p;
    };
    int* flag               = (int*)alloc(4);
    int* deg                = (int*)alloc((NN + 256) * 4);   // +tail pad for int4 scan reads
    int* cursor             = (int*)alloc(NN * 4);
    int* offs               = (int*)alloc((NN + 1) * 4);
    int* csr_src            = (int*)alloc(NE * 4);
    unsigned short* canon   = (unsigned short*)alloc(960 * 2);
    unsigned short* W1T     = (unsigned short*)alloc(256 * 256 * 2);
    unsigned short* W2T     = (unsigned short*)alloc(64 * 256 * 2);
    unsigned short* feat1   = (unsigned short*)alloc((size_t)NN * 256 * 2);
    float* el1              = (float*)alloc(NN * NH * 4);
    float* er1              = (float*)alloc(NN * NH * 4);
    unsigned short* h1      = (unsigned short*)alloc((size_t)NN * 256 * 2);
    unsigned short* feat2   = (unsigned short*)alloc((size_t)NN * 64 * 2);
    float* el2              = (float*)alloc(NN * 4);
    float* er2              = (float*)alloc(NN * 4);
    (void)ws_size; (void)in_sizes; (void)n_in; (void)out_size;

    unsigned short* cal1 = canon + 0;
    unsigned short* car1 = canon + 256;
    unsigned short* cb1  = canon + 512;
    unsigned short* cal2 = canon + 768;
    unsigned short* car2 = canon + 832;
    unsigned short* cb2  = canon + 896;

    // 1: prep (flag + canon + transposes + deg zero)
    k_prep<<<363, 256, 0, stream>>>((const unsigned short*)h, W1, W2,
                                    al1, ar1, b1, al2, ar2, b2,
                                    W1T, W2T, canon, deg, flag);
    // 2-4: CSR
    k_deg<<<(NE + 255) / 256, 256, 0, stream>>>(dst, deg, NE);
    k_scan<<<1, 256, 0, stream>>>(deg, offs, cursor, NN);
    k_scatter<<<(NE + 255) / 256, 256, 0, stream>>>(src, dst, cursor, csr_src, NE);

    // 5-6: layer 1
    k_gemm<<<dim3((NN + 127) / 128, 4), 256, 0, stream>>>(h, W1T, feat1, el1, er1,
                                                          cal1, car1, NN, 256, NH, flag);
    k_edge1<<<NN, 256, 0, stream>>>(offs, csr_src, el1, er1, feat1, cb1, h1);

    // 7-8: layer 2 (h1 known-bf16 -> flagp=nullptr)
    k_gemm<<<dim3((NN + 127) / 128, 1), 256, 0, stream>>>(h1, W2T, feat2, el2, er2,
                                                          cal2, car2, NN, 64, 1, nullptr);
    k_edge2<<<(NN + 3) / 4, 256, 0, stream>>>(offs, csr_src, el2, er2, feat2, cb2, d_out, flag);
}